// Round 4
// baseline (424.083 us; speedup 1.0000x reference)
//
#include <hip/hip_runtime.h>
#include <hip/hip_bf16.h>
#include <hip/hip_cooperative_groups.h>

namespace cg = cooperative_groups;

// Fused QKV projection: qkv = hidden[16384,1024] @ Wqkv[1024,3072] + bias,
// scattered to q/k/v [4,16,4096,64] each, fp32 out.
// R7: SINGLE cooperative kernel: {A convert + W transpose-convert} ->
// grid.sync() -> R6's persistent deep-pipelined 256x256 GEMM (verbatim).
// 256 blocks x 512 thr, 128 KiB LDS -> exactly 1 block/CU (co-resident).
// Rationale: R3/R5/R6 all show ~232 us of non-GEMM time vs ~18 us convert
// roofline -> attack launch/gap overhead by collapsing to one dispatch.

#define M_TOT 16384
#define N_TOT 3072
#define K_TOT 1024

typedef __bf16 bf16x8 __attribute__((ext_vector_type(8)));
typedef float f32x16 __attribute__((ext_vector_type(16)));

#define AS1(p) ((const __attribute__((address_space(1))) void*)(p))
#define AS3(p) ((__attribute__((address_space(3))) void*)(p))

__device__ __forceinline__ unsigned short f2bf(float f) {
    unsigned int u = __builtin_bit_cast(unsigned int, f);
    u += 0x7fffu + ((u >> 16) & 1u);
    return (unsigned short)(u >> 16);
}

__launch_bounds__(512, 2)
__global__ void qkv_fused(const float* __restrict__ hs,
                          const float* __restrict__ Wq,
                          const float* __restrict__ Wk,
                          const float* __restrict__ Wv,
                          const float* __restrict__ bq,
                          const float* __restrict__ bk,
                          const float* __restrict__ bv,
                          unsigned short* __restrict__ Abf,
                          unsigned short* __restrict__ Btbf,
                          float* __restrict__ out) {
    __shared__ __align__(16) unsigned short As[4][8192];  // 4 x 16 KiB
    __shared__ __align__(16) unsigned short Bs[4][8192];  // 4 x 16 KiB

    const int tid = threadIdx.x;

    // ================= Phase 1a: hidden fp32 -> bf16 (64 rows/block) ======
    {
        const float4* src = (const float4*)hs + (size_t)blockIdx.x * 16384;
        ushort4* dst = (ushort4*)Abf + (size_t)blockIdx.x * 16384;
#pragma unroll 4
        for (int i = tid; i < 16384; i += 512) {
            float4 v = src[i];
            ushort4 o;
            o.x = f2bf(v.x); o.y = f2bf(v.y); o.z = f2bf(v.z); o.w = f2bf(v.w);
            dst[i] = o;
        }
    }

    // ====== Phase 1b: W[k][f] -> Bt[z*1024+f][k] bf16 transpose ===========
    // 768 64x64 tiles total, 3 per block. LDS tile aliases As (8.3 KiB).
    {
        unsigned short(*tile)[65] = (unsigned short(*)[65]) & As[0][0];
        const int tx = tid & 63;
        const int ty = tid >> 6;  // 0..7
        for (int it = 0; it < 3; ++it) {
            int g = blockIdx.x * 3 + it;       // 0..767
            int z = g >> 8;                    // 0..2
            int rem = g & 255;
            int k0 = (rem >> 4) * 64;
            int f0 = (rem & 15) * 64;
            const float* W = (z == 0) ? Wq : (z == 1) ? Wk : Wv;
            __syncthreads();
#pragma unroll
            for (int r = 0; r < 8; ++r) {
                int k = ty + r * 8;
                tile[k][tx] = f2bf(W[(size_t)(k0 + k) * 1024 + f0 + tx]);
            }
            __syncthreads();
#pragma unroll
            for (int r = 0; r < 8; ++r) {
                int fr = ty + r * 8;
                Btbf[(size_t)(z * 1024 + f0 + fr) * 1024 + k0 + tx] = tile[tx][fr];
            }
        }
    }

    // ================= grid-wide sync (device-scope fence) ================
    cg::this_grid().sync();

    // ================= Phase 2: persistent GEMM (R6 verbatim) =============
    const unsigned short* __restrict__ A  = Abf;
    const unsigned short* __restrict__ Bt = Btbf;

    const int wave = tid >> 6;
    const int lane = tid & 63;
    const int r5   = lane & 31;       // row within a 32-row MFMA block
    const int half = lane >> 5;       // k-octet select within a k-step
    const int sw2  = (r5 >> 1) & 3;   // read-side swizzle term

    // persistent mapping: 256 blocks x 3 iters -> 768 tiles (64bm x 12bn).
    // supertile = 8bm x 4bn (32 tiles); st = xcd*3 + i in [0,24); bijective.
    const int xcd = blockIdx.x & 7;
    const int j   = blockIdx.x >> 3;  // 0..31
    const int jm  = j & 7;            // bm within supertile
    const int jn  = j >> 3;           // bn within supertile

    const int wr = wave >> 2;   // 0..1  -> 128-row half of A
    const int wc = wave & 3;    // 0..3  -> 64-col quarter of B

    // staging: chunk c = q*512 + tid (q=0,1); row = c>>2 = q*128 + (tid>>2),
    // slot = tid&3; slot holds octet kq = slot ^ ((row>>1)&3).
    const int tr = tid >> 2;                            // 0..127
    const int kq = (tid & 3) ^ ((tid >> 3) & 3);        // source octet
    const size_t gOff = (size_t)tr * 1024 + (size_t)kq * 8;

    int st = xcd * 3;  // supertile for i=0
    int bm = (st & 7) * 8 + jm;
    int bn = (st >> 3) * 4 + jn;
    const unsigned short* gA = A  + (size_t)bm * 256 * 1024;
    const unsigned short* gB = Bt + (size_t)bn * 256 * 1024;

#define STAGE(slot, koff, bA, bB)                                               \
    do {                                                                        \
        const unsigned short* sA_ = (bA) + (size_t)(koff) + gOff;               \
        const unsigned short* sB_ = (bB) + (size_t)(koff) + gOff;               \
        unsigned short* dA_ = &As[(slot)][wave * 512];                          \
        unsigned short* dB_ = &Bs[(slot)][wave * 512];                          \
        __builtin_amdgcn_global_load_lds(AS1(sA_), AS3(dA_), 16, 0, 0);         \
        __builtin_amdgcn_global_load_lds(AS1(sA_ + 131072), AS3(dA_ + 4096),    \
                                         16, 0, 0);                             \
        __builtin_amdgcn_global_load_lds(AS1(sB_), AS3(dB_), 16, 0, 0);         \
        __builtin_amdgcn_global_load_lds(AS1(sB_ + 131072), AS3(dB_ + 4096),    \
                                         16, 0, 0);                             \
    } while (0)

// one phase-pair: 2 K-phases of 16 from unit in ring slot `slotc`
#define PAIR(slotc)                                                             \
    do {                                                                        \
        const unsigned short* Au = &As[(slotc)][0];                             \
        const unsigned short* Bu = &Bs[(slotc)][0];                             \
        _Pragma("unroll") for (int ks = 0; ks < 2; ++ks) {                      \
            bf16x8 av[4], bvv[2];                                               \
            const int po = ((ks * 2 + half) ^ sw2) * 8;                         \
            _Pragma("unroll") for (int ib = 0; ib < 4; ++ib)                    \
                av[ib] = *(const bf16x8*)&Au[(wr * 128 + ib * 32 + r5) * 32 + po]; \
            _Pragma("unroll") for (int jb = 0; jb < 2; ++jb)                    \
                bvv[jb] = *(const bf16x8*)&Bu[(wc * 64 + jb * 32 + r5) * 32 + po]; \
            asm volatile("s_waitcnt lgkmcnt(0)" ::: "memory");                  \
            __builtin_amdgcn_sched_barrier(0);                                  \
            __builtin_amdgcn_s_setprio(1);                                      \
            _Pragma("unroll") for (int ib = 0; ib < 4; ++ib)                    \
                _Pragma("unroll") for (int jb = 0; jb < 2; ++jb)                \
                    acc[ib][jb] = __builtin_amdgcn_mfma_f32_32x32x16_bf16(      \
                        av[ib], bvv[jb], acc[ib][jb], 0, 0, 0);                 \
            __builtin_amdgcn_s_setprio(0);                                      \
        }                                                                       \
    } while (0)

#define UKOFF(u) ((size_t)(((u) >> 1) * 64 + ((u) & 1) * 32))

    // prologue: issue units 0,1,2 of iter 0 (12 loads/thread)
    STAGE(0, UKOFF(0), gA, gB);
    STAGE(1, UKOFF(1), gA, gB);
    STAGE(2, UKOFF(2), gA, gB);

    for (int i = 0; i < 3; ++i) {
        // next-iter tile (its first 3 units are staged during t=14/15)
        int bm2 = bm, bn2 = bn;
        const unsigned short *gA2 = gA, *gB2 = gB;
        if (i < 2) {
            int st2 = xcd * 3 + i + 1;
            bm2 = (st2 & 7) * 8 + jm;
            bn2 = (st2 >> 3) * 4 + jn;
            gA2 = A  + (size_t)bm2 * 256 * 1024;
            gB2 = Bt + (size_t)bn2 * 256 * 1024;
        }
        const bool lastIter = (i == 2);

        f32x16 acc[4][2] = {};

#pragma unroll 2
        for (int t = 0; t < 16; ++t) {
            // ---- pair 0: consume unit 2t; issue unit 2t+3 ----
            if (lastIter && t == 15)
                asm volatile("s_waitcnt vmcnt(4)" ::: "memory");
            else
                asm volatile("s_waitcnt vmcnt(8)" ::: "memory");
            __builtin_amdgcn_s_barrier();
            __builtin_amdgcn_sched_barrier(0);  // no ds_read above the wait
            {
                const int u = 2 * t + 3;
                if (u < 32)        STAGE(u & 3, UKOFF(u), gA, gB);
                else if (i < 2)    STAGE((u - 32) & 3, UKOFF(u - 32), gA2, gB2);
            }
            PAIR((2 * t) & 3);

            // ---- pair 1: consume unit 2t+1; issue unit 2t+4 ----
            if (lastIter && t == 15)
                asm volatile("s_waitcnt vmcnt(0)" ::: "memory");
            else
                asm volatile("s_waitcnt vmcnt(8)" ::: "memory");
            __builtin_amdgcn_s_barrier();
            __builtin_amdgcn_sched_barrier(0);
            {
                const int u = 2 * t + 4;
                if (u < 32)        STAGE(u & 3, UKOFF(u), gA, gB);
                else if (i < 2)    STAGE((u - 32) & 3, UKOFF(u - 32), gA2, gB2);
            }
            PAIR((2 * t + 1) & 3);
        }

        // Epilogue: 32x32 C/D mapping col = lane&31, row = (reg&3)+8*(reg>>2)+4*half.
        // Next-iter units 0..2 already in flight -> stores overlap prologue.
        {
            const int section = bn >> 2;                      // 0,1,2 (q/k/v)
            const int nloc0   = (bn & 3) * 256 + wc * 64;     // col within section
            const float* bias = (section == 0) ? bq : (section == 1) ? bk : bv;
            float* outsec = out + (size_t)section * (4u * 16u * 4096u * 64u);

#pragma unroll
            for (int jb = 0; jb < 2; ++jb) {
                int f = nloc0 + jb * 32 + r5;  // 0..1023 within section
                float bval = bias[f];
                int h = f >> 6, d = f & 63;
                size_t hb = (size_t)h * (4096u * 64u);
#pragma unroll
                for (int ib = 0; ib < 4; ++ib) {
                    int mbase = bm * 256 + wr * 128 + ib * 32 + 4 * half;
#pragma unroll
                    for (int reg = 0; reg < 16; ++reg) {
                        int m = mbase + (reg & 3) + 8 * (reg >> 2);
                        int b = m >> 12, s = m & 4095;
                        outsec[(size_t)b * (16u * 4096u * 64u) + hb + (size_t)s * 64u + d] =
                            acc[ib][jb][reg] + bval;
                    }
                }
            }
        }

        bm = bm2; bn = bn2; gA = gA2; gB = gB2;
    }
#undef STAGE
#undef PAIR
#undef UKOFF
}

extern "C" void kernel_launch(void* const* d_in, const int* in_sizes, int n_in,
                              void* d_out, int out_size, void* d_ws, size_t ws_size,
                              hipStream_t stream) {
    const float* hs = (const float*)d_in[0];
    const float* Wq = (const float*)d_in[1];
    const float* bq = (const float*)d_in[2];
    const float* Wk = (const float*)d_in[3];
    const float* bk = (const float*)d_in[4];
    const float* Wv = (const float*)d_in[5];
    const float* bv = (const float*)d_in[6];
    float* out = (float*)d_out;

    unsigned short* Abf  = (unsigned short*)d_ws;            // 16384*1024 bf16 = 32 MiB
    unsigned short* Btbf = Abf + (size_t)M_TOT * K_TOT;      // 3072*1024  bf16 =  6 MiB

    void* args[] = {(void*)&hs, (void*)&Wq, (void*)&Wk, (void*)&Wv,
                    (void*)&bq, (void*)&bk, (void*)&bv,
                    (void*)&Abf, (void*)&Btbf, (void*)&out};
    hipLaunchCooperativeKernel((void*)qkv_fused, dim3(256), dim3(512), args, 0,
                               stream);
}

// Round 5
// 362.916 us; speedup vs baseline: 1.1685x; 1.1685x over previous
//
#include <hip/hip_runtime.h>
#include <hip/hip_bf16.h>

// Fused QKV projection: qkv = hidden[16384,1024] @ Wqkv[1024,3072] + bias,
// scattered to q/k/v [4,16,4096,64] each, fp32 out.
// R8: back to 3 launches (R7 proved the ~205us residual is harness-fixed,
// not launch gaps). GEMM: R6 geometry (256x256, BK=64 as 2x32 units, ring-4
// LDS slots, supertile persistence) but ONE sync point per K-tile and a
// fence-free body:
//   per K-tile: __syncthreads()  ->  4x{6 ds_read, 8 MFMA} + 2 stage units
// No inner asm/vmcnt/lgkm/setprio: m97/m141 evidence says the compiler's own
// counted lgkmcnt scheduling is near-optimal inside fence-free regions; R4/R6
// fences every ~6 reads were the 72%-critical-path failure mode (m233).
// Prefetch lead stays ~1.5 K-tiles so the barrier's vmcnt(0) is
// satisfied-on-arrival (loads issued ~3000 cyc before the wait).

#define M_TOT 16384
#define N_TOT 3072
#define K_TOT 1024

typedef __bf16 bf16x8 __attribute__((ext_vector_type(8)));
typedef float f32x16 __attribute__((ext_vector_type(16)));

#define AS1(p) ((const __attribute__((address_space(1))) void*)(p))
#define AS3(p) ((__attribute__((address_space(3))) void*)(p))

__device__ __forceinline__ unsigned short f2bf(float f) {
    unsigned int u = __builtin_bit_cast(unsigned int, f);
    u += 0x7fffu + ((u >> 16) & 1u);
    return (unsigned short)(u >> 16);
}

// ---- kernel 1: hidden fp32 -> bf16, straight copy (row-major [16384][1024])
__global__ void convert_hidden(const float* __restrict__ x,
                               unsigned short* __restrict__ y, int n4) {
    int i = blockIdx.x * blockDim.x + threadIdx.x;
    int stride = gridDim.x * blockDim.x;
    for (; i < n4; i += stride) {
        float4 v = ((const float4*)x)[i];
        ushort4 o;
        o.x = f2bf(v.x); o.y = f2bf(v.y); o.z = f2bf(v.z); o.w = f2bf(v.w);
        ((ushort4*)y)[i] = o;
    }
}

// ---- kernel 2: W[k][f] fp32 -> Bt[wsel*1024 + f][k] bf16 (transpose), tiled 64x64
__global__ void convert_weights(const float* __restrict__ Wq,
                                const float* __restrict__ Wk,
                                const float* __restrict__ Wv,
                                unsigned short* __restrict__ Bt) {
    __shared__ unsigned short tile[64][65];
    const float* W = (blockIdx.z == 0) ? Wq : (blockIdx.z == 1) ? Wk : Wv;
    int k0 = blockIdx.y * 64;
    int f0 = blockIdx.x * 64;
    int tx = threadIdx.x & 63;
    int ty = threadIdx.x >> 6;  // 0..3
#pragma unroll
    for (int r = 0; r < 16; ++r) {
        int k = ty + r * 4;
        tile[k][tx] = f2bf(W[(size_t)(k0 + k) * 1024 + f0 + tx]);
    }
    __syncthreads();
#pragma unroll
    for (int r = 0; r < 16; ++r) {
        int fr = ty + r * 4;
        Bt[(size_t)(blockIdx.z * 1024 + f0 + fr) * 1024 + k0 + tx] = tile[tx][fr];
    }
}

// ---- kernel 3: persistent 256x256 GEMM, 1 barrier per K-tile, fence-free body
// A [16384][1024] bf16 row-major, Bt [3072][1024] bf16 (W^T), out fp32.
// Unit u (u = 2*ktile + khalf): rows[0,256) x k[(u>>1)*64+(u&1)*32, +32).
// LDS unit [256 rows][4 octets of 16B], row stride 64 B; octet o of row r at
// slot o ^ ((r>>1)&3) via pre-swizzled global source. Ring slot = u & 3.
__launch_bounds__(512, 2)
__global__ void qkv_gemm(const unsigned short* __restrict__ A,
                         const unsigned short* __restrict__ Bt,
                         const float* __restrict__ bq,
                         const float* __restrict__ bk,
                         const float* __restrict__ bv,
                         float* __restrict__ out) {
    __shared__ __align__(16) unsigned short As[4][8192];  // 4 x 16 KiB
    __shared__ __align__(16) unsigned short Bs[4][8192];  // 4 x 16 KiB

    const int tid  = threadIdx.x;
    const int wave = tid >> 6;
    const int lane = tid & 63;
    const int r5   = lane & 31;       // row within a 32-row MFMA block
    const int half = lane >> 5;       // k-octet select within a k-step
    const int sw2  = (r5 >> 1) & 3;   // read-side swizzle term

    // persistent mapping: 256 blocks x 3 iters -> 768 tiles (64bm x 12bn).
    // supertile = 8bm x 4bn (32 tiles); st = xcd*3 + i in [0,24); bijective.
    const int xcd = blockIdx.x & 7;
    const int j   = blockIdx.x >> 3;  // 0..31
    const int jm  = j & 7;            // bm within supertile
    const int jn  = j >> 3;           // bn within supertile

    const int wr = wave >> 2;   // 0..1  -> 128-row half of A
    const int wc = wave & 3;    // 0..3  -> 64-col quarter of B

    // staging: chunk c = q*512 + tid (q=0,1); row = c>>2 = q*128 + (tid>>2),
    // slot = tid&3; slot holds octet kq = slot ^ ((row>>1)&3).
    const int tr = tid >> 2;                            // 0..127
    const int kq = (tid & 3) ^ ((tid >> 3) & 3);        // source octet
    const size_t gOff = (size_t)tr * 1024 + (size_t)kq * 8;

    int st = xcd * 3;  // supertile for i=0
    int bm = (st & 7) * 8 + jm;
    int bn = (st >> 3) * 4 + jn;
    const unsigned short* gA = A  + (size_t)bm * 256 * 1024;
    const unsigned short* gB = Bt + (size_t)bn * 256 * 1024;

#define STAGE(slot, koff, bA, bB)                                               \
    do {                                                                        \
        const unsigned short* sA_ = (bA) + (size_t)(koff) + gOff;               \
        const unsigned short* sB_ = (bB) + (size_t)(koff) + gOff;               \
        unsigned short* dA_ = &As[(slot)][wave * 512];                          \
        unsigned short* dB_ = &Bs[(slot)][wave * 512];                          \
        __builtin_amdgcn_global_load_lds(AS1(sA_), AS3(dA_), 16, 0, 0);         \
        __builtin_amdgcn_global_load_lds(AS1(sA_ + 131072), AS3(dA_ + 4096),    \
                                         16, 0, 0);                             \
        __builtin_amdgcn_global_load_lds(AS1(sB_), AS3(dB_), 16, 0, 0);         \
        __builtin_amdgcn_global_load_lds(AS1(sB_ + 131072), AS3(dB_ + 4096),    \
                                         16, 0, 0);                             \
    } while (0)

#define UKOFF(u) ((size_t)(((u) >> 1) * 64 + ((u) & 1) * 32))

    // prologue: issue units 0,1 of iter 0 (8 loads/thread)
    STAGE(0, UKOFF(0), gA, gB);
    STAGE(1, UKOFF(1), gA, gB);

    for (int i = 0; i < 3; ++i) {
        // next-iter tile (its first units staged during t=15)
        int bm2 = bm, bn2 = bn;
        const unsigned short *gA2 = gA, *gB2 = gB;
        if (i < 2) {
            int st2 = xcd * 3 + i + 1;
            bm2 = (st2 & 7) * 8 + jm;
            bn2 = (st2 >> 3) * 4 + jn;
            gA2 = A  + (size_t)bm2 * 256 * 1024;
            gB2 = Bt + (size_t)bn2 * 256 * 1024;
        }

        f32x16 acc[4][2] = {};

#pragma unroll 2
        for (int t = 0; t < 16; ++t) {
            // ONE sync point per K-tile: waits this tile's 8 staged loads
            // (issued ~1.5 K-tiles ago -> satisfied on arrival) and joins all
            // waves (prev tile's reads done -> slots (2t+2..3)&3 reusable).
            __syncthreads();

            // fence-free body: compiler pipelines 24 ds_read vs 32 MFMA.
#pragma unroll
            for (int ks = 0; ks < 4; ++ks) {
                const int slot = (2 * t + (ks >> 1)) & 3;
                const unsigned short* Au = &As[slot][0];
                const unsigned short* Bu = &Bs[slot][0];
                bf16x8 av[4], bvv[2];
                const int po = (((ks & 1) * 2 + half) ^ sw2) * 8;
#pragma unroll
                for (int ib = 0; ib < 4; ++ib)
                    av[ib] = *(const bf16x8*)&Au[(wr * 128 + ib * 32 + r5) * 32 + po];
#pragma unroll
                for (int jb = 0; jb < 2; ++jb)
                    bvv[jb] = *(const bf16x8*)&Bu[(wc * 64 + jb * 32 + r5) * 32 + po];

                if (ks < 2) {  // stage next K-tile's units early in the body
                    const int u = 2 * t + 2 + ks;
                    if (u < 32)     STAGE(u & 3, UKOFF(u), gA, gB);
                    else if (i < 2) STAGE((u - 32) & 3, UKOFF(u - 32), gA2, gB2);
                }

#pragma unroll
                for (int ib = 0; ib < 4; ++ib)
#pragma unroll
                    for (int jb = 0; jb < 2; ++jb)
                        acc[ib][jb] = __builtin_amdgcn_mfma_f32_32x32x16_bf16(
                            av[ib], bvv[jb], acc[ib][jb], 0, 0, 0);
            }
        }

        // Epilogue: 32x32 C/D mapping col = lane&31, row = (reg&3)+8*(reg>>2)+4*half.
        // Next-iter units 0..1 already in flight -> stores overlap prologue.
        {
            const int section = bn >> 2;                      // 0,1,2 (q/k/v)
            const int nloc0   = (bn & 3) * 256 + wc * 64;     // col within section
            const float* bias = (section == 0) ? bq : (section == 1) ? bk : bv;
            float* outsec = out + (size_t)section * (4u * 16u * 4096u * 64u);

#pragma unroll
            for (int jb = 0; jb < 2; ++jb) {
                int f = nloc0 + jb * 32 + r5;  // 0..1023 within section
                float bval = bias[f];
                int h = f >> 6, d = f & 63;
                size_t hb = (size_t)h * (4096u * 64u);
#pragma unroll
                for (int ib = 0; ib < 4; ++ib) {
                    int mbase = bm * 256 + wr * 128 + ib * 32 + 4 * half;
#pragma unroll
                    for (int reg = 0; reg < 16; ++reg) {
                        int m = mbase + (reg & 3) + 8 * (reg >> 2);
                        int b = m >> 12, s = m & 4095;
                        outsec[(size_t)b * (16u * 4096u * 64u) + hb + (size_t)s * 64u + d] =
                            acc[ib][jb][reg] + bval;
                    }
                }
            }
        }

        bm = bm2; bn = bn2; gA = gA2; gB = gB2;
    }
#undef STAGE
#undef UKOFF
}

extern "C" void kernel_launch(void* const* d_in, const int* in_sizes, int n_in,
                              void* d_out, int out_size, void* d_ws, size_t ws_size,
                              hipStream_t stream) {
    const float* hs = (const float*)d_in[0];
    const float* Wq = (const float*)d_in[1];
    const float* bq = (const float*)d_in[2];
    const float* Wk = (const float*)d_in[3];
    const float* bk = (const float*)d_in[4];
    const float* Wv = (const float*)d_in[5];
    const float* bv = (const float*)d_in[6];
    float* out = (float*)d_out;

    unsigned short* Abf  = (unsigned short*)d_ws;            // 16384*1024 bf16 = 32 MiB
    unsigned short* Btbf = Abf + (size_t)M_TOT * K_TOT;      // 3072*1024  bf16 =  6 MiB

    convert_hidden<<<2048, 256, 0, stream>>>(hs, Abf, (M_TOT * K_TOT) / 4);
    convert_weights<<<dim3(16, 16, 3), 256, 0, stream>>>(Wq, Wk, Wv, Btbf);
    qkv_gemm<<<256, 512, 0, stream>>>(Abf, Btbf, bq, bk, bv, out);
}